// Round 19
// baseline (139.845 us; speedup 1.0000x reference)
//
#include <hip/hip_runtime.h>
#include <cstdint>

#define B_    4
#define T_    2048
#define DIM_  1024
#define H_    16
#define N_    64
#define BT_   8192

#define NCHUNK 64
#define CLEN   32          // T_ / NCHUNK
#define LWARM  16          // warm-up steps (contraction 0.32^16 ~ 1e-8, sub-ulp)

typedef float f32x2 __attribute__((ext_vector_type(2)));
typedef float f32x4 __attribute__((ext_vector_type(4)));
typedef short bf16x8 __attribute__((ext_vector_type(8)));
typedef unsigned short ushort_t;
typedef unsigned int uint32;

__device__ __forceinline__ float silu_f(float v) {
    return v / (1.f + __expf(-v));
}
__device__ __forceinline__ float tanh_f(float v) {
    return 1.f - 2.f / (__expf(2.f * v) + 1.f);
}
__device__ __forceinline__ ushort_t f2bf(float f) {
    uint32 u = __float_as_uint(f);
    return (ushort_t)((u + 0x7fffu + ((u >> 16) & 1u)) >> 16);   // RNE
}
// async global->LDS, 16B per lane; lds base must be wave-uniform
__device__ __forceinline__ void glds16(const void* g, void* l) {
    __builtin_amdgcn_global_load_lds(
        (const __attribute__((address_space(1))) void*)g,
        (__attribute__((address_space(3))) void*)l, 16, 0, 0);
}

// -------------------------------------------------------------------------
// K0: merged f32 -> bf16 conversion for Win / Wout only (x is fused into
// K1's A-staging now). grid = 1536, block = 256
// -------------------------------------------------------------------------
__global__ __launch_bounds__(256) void cvt2_kernel(
    const float* __restrict__ Win,  // 2097152 f32
    const float* __restrict__ Wout, // 1048576 f32
    ushort_t* __restrict__ Winb,
    ushort_t* __restrict__ Woutb)
{
    int i = blockIdx.x * 256 + threadIdx.x;
    const float* src; ushort_t* dst; int off;
    if (i < 262144) { src = Win;  dst = Winb;  off = i; }
    else            { src = Wout; dst = Woutb; off = i - 262144; }
    float4 a = ((const float4*)src)[off * 2];
    float4 b = ((const float4*)src)[off * 2 + 1];
    uint4 o;
    o.x = (uint32)f2bf(a.x) | ((uint32)f2bf(a.y) << 16);
    o.y = (uint32)f2bf(a.z) | ((uint32)f2bf(a.w) << 16);
    o.z = (uint32)f2bf(b.x) | ((uint32)f2bf(b.y) << 16);
    o.w = (uint32)f2bf(b.z) | ((uint32)f2bf(b.w) << 16);
    ((uint4*)dst)[off] = o;
}

// -------------------------------------------------------------------------
// K1: xz = X @ Win^T (M=8192,N=2048,K=1024) bf16 MFMA, 128x128 tile, BK=64,
// XOR-swizzled LDS, counted-vmcnt 2-deep ring, split px/gate outputs,
// R16 scattered-store epilogue (best measured form, 75.6us).
// NEW vs R16: A (x) is read DIRECTLY as f32 and converted to bf16 in-kernel
// (T14 reg-staging: issue f32 loads before COMPUTE(t), sched_barrier(0) to
// pin them, B glds16 issued after so A retires first in the in-order vmcnt
// queue; after COMPUTE: vmcnt(4) -> cvt -> ds_write). Eliminates the 48MB
// x-conversion pass; cvt work hides in K1's idle issue slots.
// grid = (16, 64), block = 256
// -------------------------------------------------------------------------
__global__ __launch_bounds__(256) void gemm_in_kernel(
    const float*    __restrict__ xf,    // [8192][1024] f32
    const ushort_t* __restrict__ Winb,  // [2048][1024] bf16
    const float*    __restrict__ Wx,    // [16][64][64] f32
    ushort_t*       __restrict__ pxo,   // [B,H,T,N] bf16
    ushort_t*       __restrict__ gto)   // [B,H,T,N] bf16
{
    // arena: buf(c) = +c*32768: A 16KB | B 16KB  (c = 0,1)
    //        epilogue aliases: Sb=+0 ([128][136] ushort), WxT=+34816
    __shared__ __align__(16) char arena[65536];

    const int tid  = threadIdx.x;
    const int wave = tid >> 6, lane = tid & 63;
    const int l15 = lane & 15, l4 = lane >> 4;

    // XCD-aware swizzle (1024 blocks, 8 XCDs, 128/chunk)
    const int bid = blockIdx.y * 16 + blockIdx.x;
    const int swz = (bid & 7) * 128 + (bid >> 3);
    const int bx = swz & 15;
    const int m0 = (swz >> 4) * 128;
    const int n0 = bx * 128;
    const int wr = wave >> 1, wc = wave & 1;
    const bool xhalf = (bx < 8);

    const f32x4 zero4 = {0.f, 0.f, 0.f, 0.f};
    f32x4 acc[4][4];
    #pragma unroll
    for (int mi = 0; mi < 4; ++mi)
        #pragma unroll
        for (int ni = 0; ni < 4; ++ni)
            acc[mi][ni] = zero4;

    // staging map: thread -> (row = tid>>3 in a 32-row quarter, slot tid&7)
    // source pre-swizzle: fetch element slot ((tid&7) ^ (row&7))
    const int srow = tid >> 3;                        // 0..31
    const int scol = (((tid & 7) ^ (srow & 7)) << 3); // element offset 0..56
    const ushort_t* gBb = Winb + (size_t)srow * 1024 + scol;

    float4 aReg[4][2];                  // in-flight A f32 (tile t+1)

    auto ISSUE_A = [&](int t) {
        const int k0 = t << 6;
        #pragma unroll
        for (int q = 0; q < 4; ++q) {
            const float* p = xf + (size_t)(m0 + q * 32 + srow) * 1024 + k0 + scol;
            aReg[q][0] = *(const float4*)p;
            aReg[q][1] = *(const float4*)(p + 4);
        }
    };
    auto WRITE_A = [&](int t) {
        char* bufA = arena + (t & 1) * 32768;
        #pragma unroll
        for (int q = 0; q < 4; ++q) {
            uint4 o;
            o.x = (uint32)f2bf(aReg[q][0].x) | ((uint32)f2bf(aReg[q][0].y) << 16);
            o.y = (uint32)f2bf(aReg[q][0].z) | ((uint32)f2bf(aReg[q][0].w) << 16);
            o.z = (uint32)f2bf(aReg[q][1].x) | ((uint32)f2bf(aReg[q][1].y) << 16);
            o.w = (uint32)f2bf(aReg[q][1].z) | ((uint32)f2bf(aReg[q][1].w) << 16);
            *(uint4*)(bufA + q * 4096 + tid * 16) = o;
        }
    };
    auto STAGE_B = [&](int t) {
        const int k0 = t << 6;
        char* bufB = arena + (t & 1) * 32768 + 16384;
        #pragma unroll
        for (int q = 0; q < 4; ++q)
            glds16(gBb + (size_t)(n0 + q * 32) * 1024 + k0,
                   bufB + q * 4096 + tid * 16);
    };
    // read-side swizzle: slot(kc) = ((kc*4 + l4) ^ (l15&7)); row stride 64 el
    const int sk0 = ((l4 ^ (l15 & 7)) << 3);          // element offset, kc=0
    auto COMPUTE = [&](int c) {
        const ushort_t* Aptr = (const ushort_t*)(arena + c * 32768);
        const ushort_t* Bptr = (const ushort_t*)(arena + c * 32768 + 16384);
        #pragma unroll
        for (int kc = 0; kc < 2; ++kc) {
            const int sk = sk0 ^ (kc << 5);
            bf16x8 aF[4], bF[4];
            #pragma unroll
            for (int mi = 0; mi < 4; ++mi)
                aF[mi] = *(const bf16x8*)&Aptr[(wr * 64 + mi * 16 + l15) * 64 + sk];
            #pragma unroll
            for (int ni = 0; ni < 4; ++ni)
                bF[ni] = *(const bf16x8*)&Bptr[(wc * 64 + ni * 16 + l15) * 64 + sk];
            #pragma unroll
            for (int mi = 0; mi < 4; ++mi)
                #pragma unroll
                for (int ni = 0; ni < 4; ++ni)
                    acc[mi][ni] = __builtin_amdgcn_mfma_f32_16x16x32_bf16(
                        aF[mi], bF[ni], acc[mi][ni], 0, 0, 0);
        }
    };

    // prologue: tile 0 -> buf0
    ISSUE_A(0);
    __builtin_amdgcn_sched_barrier(0);
    STAGE_B(0);
    asm volatile("s_waitcnt vmcnt(4)" : : : "memory");   // A regs ready
    WRITE_A(0);
    asm volatile("s_waitcnt vmcnt(0) lgkmcnt(0)" : : : "memory");
    __builtin_amdgcn_s_barrier();

    #pragma unroll 1
    for (int t = 0; t < 16; ++t) {
        const bool st = (t + 1 < 16);
        if (st) {
            ISSUE_A(t + 1);                       // A loads first (retire first)
            __builtin_amdgcn_sched_barrier(0);    // pin issue order
            STAGE_B(t + 1);                       // then B glds16
            asm volatile("s_waitcnt vmcnt(12)" : : : "memory");  // B(t) done
        } else {
            asm volatile("s_waitcnt vmcnt(0)" : : : "memory");
        }
        __builtin_amdgcn_s_barrier();
        COMPUTE(t & 1);
        if (st) {
            asm volatile("s_waitcnt vmcnt(4)" : : : "memory");   // A(t+1) regs
            WRITE_A(t + 1);
            asm volatile("s_waitcnt lgkmcnt(0)" : : : "memory"); // writes visible
        }
        __builtin_amdgcn_s_barrier();
    }

    if (!xhalf) {
        // gate half: silu -> bf16 -> gto (R16 scattered-store epilogue)
        const int h = bx - 8;
        #pragma unroll
        for (int mi = 0; mi < 4; ++mi)
            #pragma unroll
            for (int ni = 0; ni < 4; ++ni) {
                int col = (h << 7) + wc * 64 + ni * 16 + l15;
                int hh = col >> 6, n = col & 63;
                #pragma unroll
                for (int r = 0; r < 4; ++r) {
                    int row = m0 + wr * 64 + mi * 16 + l4 * 4 + r;
                    int b = row >> 11, t = row & 2047;
                    size_t idx = ((size_t)((b << 4) + hh) * 2048 + t) * 64 + n;
                    gto[idx] = f2bf(silu_f(acc[mi][ni][r]));
                }
            }
    } else {
        // x half: stage S = silu(acc) and WxT into arena (k-loop bufs dead)
        ushort_t (*Sb)[136] = (ushort_t(*)[136])arena;
        ushort_t (*WxT)[64][72] = (ushort_t(*)[64][72])(arena + 34816);

        __syncthreads();
        for (int q = tid; q < 8192; q += 256) {
            int hh = q >> 12, rem = q & 4095, i = rem >> 6, jj = rem & 63;
            WxT[hh][jj][i] = f2bf(Wx[(((bx << 1) + hh) << 12) + (i << 6) + jj]);
        }
        #pragma unroll
        for (int mi = 0; mi < 4; ++mi)
            #pragma unroll
            for (int ni = 0; ni < 4; ++ni) {
                int col = wc * 64 + ni * 16 + l15;
                #pragma unroll
                for (int r = 0; r < 4; ++r) {
                    int row = wr * 64 + mi * 16 + l4 * 4 + r;
                    Sb[row][col] = f2bf(silu_f(acc[mi][ni][r]));
                }
            }
        __syncthreads();
        #pragma unroll
        for (int hh = 0; hh < 2; ++hh) {
            f32x4 acc2[2][4];
            #pragma unroll
            for (int mf = 0; mf < 2; ++mf)
                #pragma unroll
                for (int nf = 0; nf < 4; ++nf)
                    acc2[mf][nf] = zero4;
            #pragma unroll
            for (int ks = 0; ks < 2; ++ks) {
                bf16x8 a2[2], b2[4];
                #pragma unroll
                for (int mf = 0; mf < 2; ++mf)
                    a2[mf] = *(const bf16x8*)&Sb[wave * 32 + mf * 16 + l15]
                                                [hh * 64 + ks * 32 + l4 * 8];
                #pragma unroll
                for (int nf = 0; nf < 4; ++nf)
                    b2[nf] = *(const bf16x8*)&WxT[hh][nf * 16 + l15][ks * 32 + l4 * 8];
                #pragma unroll
                for (int mf = 0; mf < 2; ++mf)
                    #pragma unroll
                    for (int nf = 0; nf < 4; ++nf)
                        acc2[mf][nf] = __builtin_amdgcn_mfma_f32_16x16x32_bf16(
                            a2[mf], b2[nf], acc2[mf][nf], 0, 0, 0);
            }
            const int hg = (bx << 1) + hh;
            #pragma unroll
            for (int mf = 0; mf < 2; ++mf)
                #pragma unroll
                for (int nf = 0; nf < 4; ++nf) {
                    int jj = nf * 16 + l15;
                    #pragma unroll
                    for (int r = 0; r < 4; ++r) {
                        int row = m0 + wave * 32 + mf * 16 + l4 * 4 + r;
                        int b = row >> 11, t = row & 2047;
                        size_t idx = ((size_t)((b << 4) + hg) * 2048 + t) * 64 + jj;
                        pxo[idx] = f2bf(acc2[mf][nf][r]);
                    }
                }
        }
    }
}

// -------------------------------------------------------------------------
// K2: CHUNKED Elman scan (R16, unchanged). NCHUNK 64, LWARM 16, split
// px/gate bf16 inputs, LDS-staged burst-flushed output.
// grid = 4096, block = 64
// -------------------------------------------------------------------------
__global__ __launch_bounds__(64) void scan_kernel(
    const ushort_t* __restrict__ pxg,  // [B,H,T,N] bf16
    const ushort_t* __restrict__ gtg,  // [B,H,T,N] bf16
    ushort_t* __restrict__ og,         // out bf16 [B,H,T,N]
    const float* __restrict__ Wh,
    const float* __restrict__ bias,
    const float* __restrict__ h0,
    float* __restrict__ hfin)
{
    const int bh = blockIdx.x >> 6;      // b*16 + h
    const int c  = blockIdx.x & 63;      // chunk
    const int h = bh & 15;
    const int j = threadIdx.x;
    __shared__ float sh[64];
    __shared__ ushort_t stg[512];        // 8 steps x 64 lanes staged output

    f32x2 w2[32];
    #pragma unroll
    for (int i = 0; i < 32; ++i) {
        w2[i].x = Wh[(h << 12) + ((2 * i) << 6) + j];
        w2[i].y = Wh[(h << 12) + ((2 * i + 1) << 6) + j];
    }
    const float bj = bias[(h << 6) + j];

    const int nwarm = (c == 0) ? 0 : LWARM;
    const int S = nwarm + CLEN;          // total steps this chunk
    const int t_begin = c * CLEN - nwarm;

    sh[j] = (c == 0) ? h0[(bh << 6) + j] : 0.f;
    __syncthreads();

    const ushort_t* px_p = pxg + ((size_t)bh << 17) + ((size_t)t_begin << 6);
    const ushort_t* gt_p = gtg + ((size_t)bh << 17) + ((size_t)t_begin << 6);
    ushort_t* og_p = og + ((size_t)bh << 17) + ((size_t)(c * CLEN) << 6);

    ushort_t pxr[8], gr[8];
    #pragma unroll
    for (int u = 0; u < 8; ++u) {
        pxr[u] = px_p[(u << 6) + j];
        gr[u]  = gt_p[(u << 6) + j];
    }

    float hn = 0.f;

#define SCAN_BODY(T_ABS, U, DO_STG)                                       \
    do {                                                                  \
        const uint32 vp = pxr[U];                                         \
        const uint32 vg = gr[U];                                          \
        int tn = (T_ABS) + 8;                                             \
        if (tn > S - 1) tn = S - 1;                                       \
        pxr[U] = px_p[(tn << 6) + j];                                     \
        gr[U]  = gt_p[(tn << 6) + j];                                     \
        const float px = __uint_as_float(vp << 16);                       \
        f32x2 a0 = {px + bj, 0.f};                                        \
        f32x2 a1 = {0.f, 0.f}, a2 = {0.f, 0.f}, a3 = {0.f, 0.f};          \
        _Pragma("unroll")                                                 \
        for (int i_ = 0; i_ < 8; ++i_) {                                  \
            float4 hv0 = *(const float4*)&sh[(i_ << 3) + 0];              \
            float4 hv1 = *(const float4*)&sh[(i_ << 3) + 4];              \
            f32x2 h01 = {hv0.x, hv0.y}, h23 = {hv0.z, hv0.w};             \
            f32x2 h45 = {hv1.x, hv1.y}, h67 = {hv1.z, hv1.w};             \
            a0 = h01 * w2[(i_ << 2) + 0] + a0;                            \
            a1 = h23 * w2[(i_ << 2) + 1] + a1;                            \
            a2 = h45 * w2[(i_ << 2) + 2] + a2;                            \
            a3 = h67 * w2[(i_ << 2) + 3] + a3;                            \
        }                                                                 \
        float a_ = ((a0.x + a0.y) + (a1.x + a1.y)) +                      \
                   ((a2.x + a2.y) + (a3.x + a3.y));                       \
        hn = tanh_f(a_);                                                  \
        if (DO_STG) {                                                     \
            const float g_ = __uint_as_float(vg << 16);                   \
            stg[(U << 6) + j] = f2bf(hn * g_);                            \
        }                                                                 \
        __builtin_amdgcn_wave_barrier();                                  \
        sh[j] = hn;                                                       \
        __builtin_amdgcn_wave_barrier();                                  \
    } while (0)

    for (int t0 = 0; t0 < nwarm; t0 += 8) {
        #pragma unroll
        for (int u = 0; u < 8; ++u)
            SCAN_BODY(t0 + u, u, false);
    }
    for (int t0 = nwarm; t0 < S; t0 += 8) {
        #pragma unroll
        for (int u = 0; u < 8; ++u)
            SCAN_BODY(t0 + u, u, true);
        int4 wv = *(const int4*)&stg[j << 3];
        *(int4*)(og_p + ((size_t)(t0 - nwarm) << 6) + (j << 3)) = wv;
    }
#undef SCAN_BODY

    if (c == NCHUNK - 1)
        hfin[(bh << 6) + j] = hn;
}

// -------------------------------------------------------------------------
// K3: out = og @ Wout^T (M=8192,N=1024,K=1024) bf16 MFMA, 128x128 tile.
// R13 structure (BK=64, XOR swizzle, 2-deep ring), no setprio.
// grid = (8, 64), block = 256
// -------------------------------------------------------------------------
__global__ __launch_bounds__(256) void gemm_out_kernel(
    const ushort_t* __restrict__ og,     // [B,H,T,N] bf16
    const ushort_t* __restrict__ Woutb,  // [1024][1024] bf16
    float* __restrict__ out)             // [8192][1024] f32
{
    __shared__ __align__(16) char arena[65536];   // 2 bufs x 32KB

    const int tid  = threadIdx.x;
    const int wave = tid >> 6, lane = tid & 63;
    const int l15 = lane & 15, l4 = lane >> 4;

    const int bid = blockIdx.y * 8 + blockIdx.x;
    const int swz = (bid & 7) * 64 + (bid >> 3);
    const int m0 = (swz >> 3) * 128;
    const int n0 = (swz & 7) * 128;
    const int wr = wave >> 1, wc = wave & 1;

    const f32x4 zero4 = {0.f, 0.f, 0.f, 0.f};
    f32x4 acc[4][4];
    #pragma unroll
    for (int mi = 0; mi < 4; ++mi)
        #pragma unroll
        for (int ni = 0; ni < 4; ++ni)
            acc[mi][ni] = zero4;

    const int srow = tid >> 3;                        // 0..31
    const int scol = (((tid & 7) ^ (srow & 7)) << 3); // element offset 0..56
    const ushort_t* gBb = Woutb + (size_t)srow * 1024 + scol;

    int qb[4], qt[4];
    #pragma unroll
    for (int q = 0; q < 4; ++q) {
        int m = m0 + q * 32 + srow;
        qb[q] = m >> 11; qt[q] = m & 2047;
    }

    auto STAGE = [&](int t, int c) {
        const int k0 = t << 6;
        const int he = t;                 // k0>>6: BK=64 aligns with heads
        char* bufA = arena + c * 32768;
        char* bufB = bufA + 16384;
        #pragma unroll
        for (int q = 0; q < 4; ++q) {
            const ushort_t* ap = og +
                ((size_t)((qb[q] << 4) + he) * 2048 + qt[q]) * 64 + scol;
            glds16(ap, bufA + q * 4096 + tid * 16);
        }
        #pragma unroll
        for (int q = 0; q < 4; ++q)
            glds16(gBb + (size_t)(n0 + q * 32) * 1024 + k0,
                   bufB + q * 4096 + tid * 16);
    };
    const int sk0 = ((l4 ^ (l15 & 7)) << 3);
    auto COMPUTE = [&](int c) {
        const ushort_t* Aptr = (const ushort_t*)(arena + c * 32768);
        const ushort_t* Bptr = (const ushort_t*)(arena + c * 32768 + 16384);
        #pragma unroll
        for (int kc = 0; kc < 2; ++kc) {
            const int sk = sk0 ^ (kc << 5);
            bf16x8 aF[4], bF[4];
            #pragma unroll
            for (int mi = 0; mi < 4; ++mi)
                aF[mi] = *(const bf16x8*)&Aptr[(wr * 64 + mi * 16 + l15) * 64 + sk];
            #pragma unroll
            for (int ni = 0; ni < 4; ++ni)
                bF[ni] = *(const bf16x8*)&Bptr[(wc * 64 + ni * 16 + l15) * 64 + sk];
            #pragma unroll
            for (int mi = 0; mi < 4; ++mi)
                #pragma unroll
                for (int ni = 0; ni < 4; ++ni)
                    acc[mi][ni] = __builtin_amdgcn_mfma_f32_16x16x32_bf16(
                        aF[mi], bF[ni], acc[mi][ni], 0, 0, 0);
        }
    };

    STAGE(0, 0);
    #pragma unroll 1
    for (int t = 0; t < 16; ++t) {
        if (t + 1 < 16) {
            STAGE(t + 1, (t + 1) & 1);
            asm volatile("s_waitcnt vmcnt(8)" : : : "memory");
        } else {
            asm volatile("s_waitcnt vmcnt(0)" : : : "memory");
        }
        __builtin_amdgcn_s_barrier();
        COMPUTE(t & 1);
        __builtin_amdgcn_s_barrier();
    }

    #pragma unroll
    for (int mi = 0; mi < 4; ++mi)
        #pragma unroll
        for (int ni = 0; ni < 4; ++ni) {
            int d = n0 + wc * 64 + ni * 16 + l15;
            #pragma unroll
            for (int r = 0; r < 4; ++r) {
                int row = m0 + wr * 64 + mi * 16 + l4 * 4 + r;
                out[(size_t)row * 1024 + d] = acc[mi][ni][r];
            }
        }
}

// -------------------------------------------------------------------------
extern "C" void kernel_launch(void* const* d_in, const int* in_sizes, int n_in,
                              void* d_out, int out_size, void* d_ws, size_t ws_size,
                              hipStream_t stream)
{
    const float* x    = (const float*)d_in[0];
    const float* h0   = (const float*)d_in[1];
    const float* Win  = (const float*)d_in[2];
    const float* Wx   = (const float*)d_in[3];
    const float* Wh   = (const float*)d_in[4];
    const float* bias = (const float*)d_in[5];
    const float* Wout = (const float*)d_in[6];

    float* out  = (float*)d_out;
    float* hfin = out + (size_t)BT_ * DIM_;

    // ws layout:
    char* ws = (char*)d_ws;
    ushort_t* pxb   = (ushort_t*)(ws);                      // 16 MB bf16 px
    ushort_t* gtb   = (ushort_t*)(ws + 16777216);           // 16 MB bf16 gate
    ushort_t* ogb   = (ushort_t*)(ws + 33554432);           // 16 MB bf16 og
    ushort_t* Winb  = (ushort_t*)(ws + 50331648);           //  4 MB
    ushort_t* Woutb = (ushort_t*)(ws + 54525952);           //  2 MB

    cvt2_kernel<<<1536, 256, 0, stream>>>(Win, Wout, Winb, Woutb);

    gemm_in_kernel<<<dim3(16, 64), 256, 0, stream>>>(x, Winb, Wx, pxb, gtb);
    scan_kernel<<<64 * NCHUNK, 64, 0, stream>>>(pxb, gtb, ogb, Wh, bias, h0, hfin);
    gemm_out_kernel<<<dim3(8, 64), 256, 0, stream>>>(ogb, Woutb, out);
}

// Round 20
// 120.088 us; speedup vs baseline: 1.1645x; 1.1645x over previous
//
#include <hip/hip_runtime.h>
#include <cstdint>

#define B_    4
#define T_    2048
#define DIM_  1024
#define H_    16
#define N_    64
#define BT_   8192

#define NCHUNK 64
#define CLEN   32          // T_ / NCHUNK
#define LWARM  16          // warm-up steps (contraction 0.32^16 ~ 1e-8, sub-ulp)

typedef float f32x2 __attribute__((ext_vector_type(2)));
typedef float f32x4 __attribute__((ext_vector_type(4)));
typedef short bf16x8 __attribute__((ext_vector_type(8)));
typedef unsigned short ushort_t;
typedef unsigned int uint32;

__device__ __forceinline__ float silu_f(float v) {
    return v / (1.f + __expf(-v));
}
__device__ __forceinline__ float tanh_f(float v) {
    return 1.f - 2.f / (__expf(2.f * v) + 1.f);
}
__device__ __forceinline__ ushort_t f2bf(float f) {
    uint32 u = __float_as_uint(f);
    return (ushort_t)((u + 0x7fffu + ((u >> 16) & 1u)) >> 16);   // RNE
}
// async global->LDS, 16B per lane; lds base must be wave-uniform
__device__ __forceinline__ void glds16(const void* g, void* l) {
    __builtin_amdgcn_global_load_lds(
        (const __attribute__((address_space(1))) void*)g,
        (__attribute__((address_space(3))) void*)l, 16, 0, 0);
}

// -------------------------------------------------------------------------
// K0: merged f32 -> bf16 conversion for x / Win / Wout in ONE launch.
// grid = 5632, block = 256
// -------------------------------------------------------------------------
__global__ __launch_bounds__(256) void cvt3_kernel(
    const float* __restrict__ x,    // 8388608 f32
    const float* __restrict__ Win,  // 2097152 f32
    const float* __restrict__ Wout, // 1048576 f32
    ushort_t* __restrict__ xw,
    ushort_t* __restrict__ Winb,
    ushort_t* __restrict__ Woutb)
{
    int i = blockIdx.x * 256 + threadIdx.x;
    const float* src; ushort_t* dst; int off;
    if (i < 1048576)      { src = x;    dst = xw;    off = i; }
    else if (i < 1310720) { src = Win;  dst = Winb;  off = i - 1048576; }
    else                  { src = Wout; dst = Woutb; off = i - 1310720; }
    float4 a = ((const float4*)src)[off * 2];
    float4 b = ((const float4*)src)[off * 2 + 1];
    uint4 o;
    o.x = (uint32)f2bf(a.x) | ((uint32)f2bf(a.y) << 16);
    o.y = (uint32)f2bf(a.z) | ((uint32)f2bf(a.w) << 16);
    o.z = (uint32)f2bf(b.x) | ((uint32)f2bf(b.y) << 16);
    o.w = (uint32)f2bf(b.z) | ((uint32)f2bf(b.w) << 16);
    ((uint4*)dst)[off] = o;
}

// -------------------------------------------------------------------------
// K1: xz = X @ Win^T (M=8192,N=2048,K=1024) bf16 MFMA, 128x128 tile, BK=64,
// XOR-swizzled LDS, 2-deep ring, counted vmcnt(8), split px/gate stores.
// EXACT R16 form (best measured: 75.6us).
// grid = (16, 64), block = 256
// -------------------------------------------------------------------------
__global__ __launch_bounds__(256) void gemm_in_kernel(
    const ushort_t* __restrict__ xw,    // [8192][1024] bf16
    const ushort_t* __restrict__ Winb,  // [2048][1024] bf16
    const float*    __restrict__ Wx,    // [16][64][64] f32
    ushort_t*       __restrict__ pxo,   // [B,H,T,N] bf16
    ushort_t*       __restrict__ gto)   // [B,H,T,N] bf16
{
    // arena: buf(c) = +c*32768: A 16KB | B 16KB  (c = 0,1)
    //        epilogue aliases: Sb=+0 ([128][136] ushort), WxT=+34816
    __shared__ __align__(16) char arena[65536];

    const int tid  = threadIdx.x;
    const int wave = tid >> 6, lane = tid & 63;
    const int l15 = lane & 15, l4 = lane >> 4;

    // XCD-aware swizzle (1024 blocks, 8 XCDs, 128/chunk)
    const int bid = blockIdx.y * 16 + blockIdx.x;
    const int swz = (bid & 7) * 128 + (bid >> 3);
    const int bx = swz & 15;
    const int m0 = (swz >> 4) * 128;
    const int n0 = bx * 128;
    const int wr = wave >> 1, wc = wave & 1;
    const bool xhalf = (bx < 8);

    const f32x4 zero4 = {0.f, 0.f, 0.f, 0.f};
    f32x4 acc[4][4];
    #pragma unroll
    for (int mi = 0; mi < 4; ++mi)
        #pragma unroll
        for (int ni = 0; ni < 4; ++ni)
            acc[mi][ni] = zero4;

    // staging map: thread -> (row = tid>>3 in a 32-row quarter, c16 = tid&7)
    // source pre-swizzle: fetch global column slot (c16 ^ (row&7))
    const int srow = tid >> 3;                       // 0..31
    const int scol = (((tid & 7) ^ (srow & 7)) << 3); // element offset 0..56
    const ushort_t* gAb = xw   + (size_t)srow * 1024 + scol;
    const ushort_t* gBb = Winb + (size_t)srow * 1024 + scol;

    auto STAGE = [&](int t, int c) {
        const int k0 = t << 6;
        char* bufA = arena + c * 32768;
        char* bufB = bufA + 16384;
        #pragma unroll
        for (int q = 0; q < 4; ++q)
            glds16(gAb + (size_t)(m0 + q * 32) * 1024 + k0,
                   bufA + q * 4096 + tid * 16);
        #pragma unroll
        for (int q = 0; q < 4; ++q)
            glds16(gBb + (size_t)(n0 + q * 32) * 1024 + k0,
                   bufB + q * 4096 + tid * 16);
    };
    // read-side swizzle: slot(kc) = ((kc*4 + l4) ^ (l15&7)); row stride 64 el
    const int sk0 = ((l4 ^ (l15 & 7)) << 3);         // element offset, kc=0
    auto COMPUTE = [&](int c) {
        const ushort_t* Aptr = (const ushort_t*)(arena + c * 32768);
        const ushort_t* Bptr = (const ushort_t*)(arena + c * 32768 + 16384);
        #pragma unroll
        for (int kc = 0; kc < 2; ++kc) {
            const int sk = sk0 ^ (kc << 5);
            bf16x8 aF[4], bF[4];
            #pragma unroll
            for (int mi = 0; mi < 4; ++mi)
                aF[mi] = *(const bf16x8*)&Aptr[(wr * 64 + mi * 16 + l15) * 64 + sk];
            #pragma unroll
            for (int ni = 0; ni < 4; ++ni)
                bF[ni] = *(const bf16x8*)&Bptr[(wc * 64 + ni * 16 + l15) * 64 + sk];
            #pragma unroll
            for (int mi = 0; mi < 4; ++mi)
                #pragma unroll
                for (int ni = 0; ni < 4; ++ni)
                    acc[mi][ni] = __builtin_amdgcn_mfma_f32_16x16x32_bf16(
                        aF[mi], bF[ni], acc[mi][ni], 0, 0, 0);
        }
    };

    STAGE(0, 0);
    #pragma unroll 1
    for (int t = 0; t < 16; ++t) {
        if (t + 1 < 16) {
            STAGE(t + 1, (t + 1) & 1);
            asm volatile("s_waitcnt vmcnt(8)" : : : "memory");
        } else {
            asm volatile("s_waitcnt vmcnt(0)" : : : "memory");
        }
        __builtin_amdgcn_s_barrier();
        COMPUTE(t & 1);
        __builtin_amdgcn_s_barrier();
    }

    if (!xhalf) {
        // gate half: silu -> bf16 -> gto
        const int h = bx - 8;
        #pragma unroll
        for (int mi = 0; mi < 4; ++mi)
            #pragma unroll
            for (int ni = 0; ni < 4; ++ni) {
                int col = (h << 7) + wc * 64 + ni * 16 + l15;
                int hh = col >> 6, n = col & 63;
                #pragma unroll
                for (int r = 0; r < 4; ++r) {
                    int row = m0 + wr * 64 + mi * 16 + l4 * 4 + r;
                    int b = row >> 11, t = row & 2047;
                    size_t idx = ((size_t)((b << 4) + hh) * 2048 + t) * 64 + n;
                    gto[idx] = f2bf(silu_f(acc[mi][ni][r]));
                }
            }
    } else {
        // x half: stage S = silu(acc) and WxT into arena (k-loop bufs dead)
        ushort_t (*Sb)[136] = (ushort_t(*)[136])arena;
        ushort_t (*WxT)[64][72] = (ushort_t(*)[64][72])(arena + 34816);

        for (int q = tid; q < 8192; q += 256) {
            int hh = q >> 12, rem = q & 4095, i = rem >> 6, jj = rem & 63;
            WxT[hh][jj][i] = f2bf(Wx[(((bx << 1) + hh) << 12) + (i << 6) + jj]);
        }
        #pragma unroll
        for (int mi = 0; mi < 4; ++mi)
            #pragma unroll
            for (int ni = 0; ni < 4; ++ni) {
                int col = wc * 64 + ni * 16 + l15;
                #pragma unroll
                for (int r = 0; r < 4; ++r) {
                    int row = wr * 64 + mi * 16 + l4 * 4 + r;
                    Sb[row][col] = f2bf(silu_f(acc[mi][ni][r]));
                }
            }
        __syncthreads();
        #pragma unroll
        for (int hh = 0; hh < 2; ++hh) {
            f32x4 acc2[2][4];
            #pragma unroll
            for (int mf = 0; mf < 2; ++mf)
                #pragma unroll
                for (int nf = 0; nf < 4; ++nf)
                    acc2[mf][nf] = zero4;
            #pragma unroll
            for (int ks = 0; ks < 2; ++ks) {
                bf16x8 a2[2], b2[4];
                #pragma unroll
                for (int mf = 0; mf < 2; ++mf)
                    a2[mf] = *(const bf16x8*)&Sb[wave * 32 + mf * 16 + l15]
                                                [hh * 64 + ks * 32 + l4 * 8];
                #pragma unroll
                for (int nf = 0; nf < 4; ++nf)
                    b2[nf] = *(const bf16x8*)&WxT[hh][nf * 16 + l15][ks * 32 + l4 * 8];
                #pragma unroll
                for (int mf = 0; mf < 2; ++mf)
                    #pragma unroll
                    for (int nf = 0; nf < 4; ++nf)
                        acc2[mf][nf] = __builtin_amdgcn_mfma_f32_16x16x32_bf16(
                            a2[mf], b2[nf], acc2[mf][nf], 0, 0, 0);
            }
            const int hg = (bx << 1) + hh;
            #pragma unroll
            for (int mf = 0; mf < 2; ++mf)
                #pragma unroll
                for (int nf = 0; nf < 4; ++nf) {
                    int jj = nf * 16 + l15;
                    #pragma unroll
                    for (int r = 0; r < 4; ++r) {
                        int row = m0 + wave * 32 + mf * 16 + l4 * 4 + r;
                        int b = row >> 11, t = row & 2047;
                        size_t idx = ((size_t)((b << 4) + hg) * 2048 + t) * 64 + jj;
                        pxo[idx] = f2bf(acc2[mf][nf][r]);
                    }
                }
        }
    }
}

// -------------------------------------------------------------------------
// K2: CHUNKED Elman scan (R16, unchanged). NCHUNK 64, LWARM 16, split
// px/gate bf16 inputs, LDS-staged burst-flushed output.
// grid = 4096, block = 64
// -------------------------------------------------------------------------
__global__ __launch_bounds__(64) void scan_kernel(
    const ushort_t* __restrict__ pxg,  // [B,H,T,N] bf16
    const ushort_t* __restrict__ gtg,  // [B,H,T,N] bf16
    ushort_t* __restrict__ og,         // out bf16 [B,H,T,N]
    const float* __restrict__ Wh,
    const float* __restrict__ bias,
    const float* __restrict__ h0,
    float* __restrict__ hfin)
{
    const int bh = blockIdx.x >> 6;      // b*16 + h
    const int c  = blockIdx.x & 63;      // chunk
    const int h = bh & 15;
    const int j = threadIdx.x;
    __shared__ float sh[64];
    __shared__ ushort_t stg[512];        // 8 steps x 64 lanes staged output

    f32x2 w2[32];
    #pragma unroll
    for (int i = 0; i < 32; ++i) {
        w2[i].x = Wh[(h << 12) + ((2 * i) << 6) + j];
        w2[i].y = Wh[(h << 12) + ((2 * i + 1) << 6) + j];
    }
    const float bj = bias[(h << 6) + j];

    const int nwarm = (c == 0) ? 0 : LWARM;
    const int S = nwarm + CLEN;          // total steps this chunk
    const int t_begin = c * CLEN - nwarm;

    sh[j] = (c == 0) ? h0[(bh << 6) + j] : 0.f;
    __syncthreads();

    const ushort_t* px_p = pxg + ((size_t)bh << 17) + ((size_t)t_begin << 6);
    const ushort_t* gt_p = gtg + ((size_t)bh << 17) + ((size_t)t_begin << 6);
    ushort_t* og_p = og + ((size_t)bh << 17) + ((size_t)(c * CLEN) << 6);

    ushort_t pxr[8], gr[8];
    #pragma unroll
    for (int u = 0; u < 8; ++u) {
        pxr[u] = px_p[(u << 6) + j];
        gr[u]  = gt_p[(u << 6) + j];
    }

    float hn = 0.f;

#define SCAN_BODY(T_ABS, U, DO_STG)                                       \
    do {                                                                  \
        const uint32 vp = pxr[U];                                         \
        const uint32 vg = gr[U];                                          \
        int tn = (T_ABS) + 8;                                             \
        if (tn > S - 1) tn = S - 1;                                       \
        pxr[U] = px_p[(tn << 6) + j];                                     \
        gr[U]  = gt_p[(tn << 6) + j];                                     \
        const float px = __uint_as_float(vp << 16);                       \
        f32x2 a0 = {px + bj, 0.f};                                        \
        f32x2 a1 = {0.f, 0.f}, a2 = {0.f, 0.f}, a3 = {0.f, 0.f};          \
        _Pragma("unroll")                                                 \
        for (int i_ = 0; i_ < 8; ++i_) {                                  \
            float4 hv0 = *(const float4*)&sh[(i_ << 3) + 0];              \
            float4 hv1 = *(const float4*)&sh[(i_ << 3) + 4];              \
            f32x2 h01 = {hv0.x, hv0.y}, h23 = {hv0.z, hv0.w};             \
            f32x2 h45 = {hv1.x, hv1.y}, h67 = {hv1.z, hv1.w};             \
            a0 = h01 * w2[(i_ << 2) + 0] + a0;                            \
            a1 = h23 * w2[(i_ << 2) + 1] + a1;                            \
            a2 = h45 * w2[(i_ << 2) + 2] + a2;                            \
            a3 = h67 * w2[(i_ << 2) + 3] + a3;                            \
        }                                                                 \
        float a_ = ((a0.x + a0.y) + (a1.x + a1.y)) +                      \
                   ((a2.x + a2.y) + (a3.x + a3.y));                       \
        hn = tanh_f(a_);                                                  \
        if (DO_STG) {                                                     \
            const float g_ = __uint_as_float(vg << 16);                   \
            stg[(U << 6) + j] = f2bf(hn * g_);                            \
        }                                                                 \
        __builtin_amdgcn_wave_barrier();                                  \
        sh[j] = hn;                                                       \
        __builtin_amdgcn_wave_barrier();                                  \
    } while (0)

    for (int t0 = 0; t0 < nwarm; t0 += 8) {
        #pragma unroll
        for (int u = 0; u < 8; ++u)
            SCAN_BODY(t0 + u, u, false);
    }
    for (int t0 = nwarm; t0 < S; t0 += 8) {
        #pragma unroll
        for (int u = 0; u < 8; ++u)
            SCAN_BODY(t0 + u, u, true);
        int4 wv = *(const int4*)&stg[j << 3];
        *(int4*)(og_p + ((size_t)(t0 - nwarm) << 6) + (j << 3)) = wv;
    }
#undef SCAN_BODY

    if (c == NCHUNK - 1)
        hfin[(bh << 6) + j] = hn;
}

// -------------------------------------------------------------------------
// K3: out = og @ Wout^T (M=8192,N=1024,K=1024) bf16 MFMA, 128x128 tile.
// R13 structure (BK=64, XOR swizzle, 2-deep ring), no setprio.
// grid = (8, 64), block = 256
// -------------------------------------------------------------------------
__global__ __launch_bounds__(256) void gemm_out_kernel(
    const ushort_t* __restrict__ og,     // [B,H,T,N] bf16
    const ushort_t* __restrict__ Woutb,  // [1024][1024] bf16
    float* __restrict__ out)             // [8192][1024] f32
{
    __shared__ __align__(16) char arena[65536];   // 2 bufs x 32KB

    const int tid  = threadIdx.x;
    const int wave = tid >> 6, lane = tid & 63;
    const int l15 = lane & 15, l4 = lane >> 4;

    const int bid = blockIdx.y * 8 + blockIdx.x;
    const int swz = (bid & 7) * 64 + (bid >> 3);
    const int m0 = (swz >> 3) * 128;
    const int n0 = (swz & 7) * 128;
    const int wr = wave >> 1, wc = wave & 1;

    const f32x4 zero4 = {0.f, 0.f, 0.f, 0.f};
    f32x4 acc[4][4];
    #pragma unroll
    for (int mi = 0; mi < 4; ++mi)
        #pragma unroll
        for (int ni = 0; ni < 4; ++ni)
            acc[mi][ni] = zero4;

    const int srow = tid >> 3;                        // 0..31
    const int scol = (((tid & 7) ^ (srow & 7)) << 3); // element offset 0..56
    const ushort_t* gBb = Woutb + (size_t)srow * 1024 + scol;

    int qb[4], qt[4];
    #pragma unroll
    for (int q = 0; q < 4; ++q) {
        int m = m0 + q * 32 + srow;
        qb[q] = m >> 11; qt[q] = m & 2047;
    }

    auto STAGE = [&](int t, int c) {
        const int k0 = t << 6;
        const int he = t;                 // k0>>6: BK=64 aligns with heads
        char* bufA = arena + c * 32768;
        char* bufB = bufA + 16384;
        #pragma unroll
        for (int q = 0; q < 4; ++q) {
            const ushort_t* ap = og +
                ((size_t)((qb[q] << 4) + he) * 2048 + qt[q]) * 64 + scol;
            glds16(ap, bufA + q * 4096 + tid * 16);
        }
        #pragma unroll
        for (int q = 0; q < 4; ++q)
            glds16(gBb + (size_t)(n0 + q * 32) * 1024 + k0,
                   bufB + q * 4096 + tid * 16);
    };
    const int sk0 = ((l4 ^ (l15 & 7)) << 3);
    auto COMPUTE = [&](int c) {
        const ushort_t* Aptr = (const ushort_t*)(arena + c * 32768);
        const ushort_t* Bptr = (const ushort_t*)(arena + c * 32768 + 16384);
        #pragma unroll
        for (int kc = 0; kc < 2; ++kc) {
            const int sk = sk0 ^ (kc << 5);
            bf16x8 aF[4], bF[4];
            #pragma unroll
            for (int mi = 0; mi < 4; ++mi)
                aF[mi] = *(const bf16x8*)&Aptr[(wr * 64 + mi * 16 + l15) * 64 + sk];
            #pragma unroll
            for (int ni = 0; ni < 4; ++ni)
                bF[ni] = *(const bf16x8*)&Bptr[(wc * 64 + ni * 16 + l15) * 64 + sk];
            #pragma unroll
            for (int mi = 0; mi < 4; ++mi)
                #pragma unroll
                for (int ni = 0; ni < 4; ++ni)
                    acc[mi][ni] = __builtin_amdgcn_mfma_f32_16x16x32_bf16(
                        aF[mi], bF[ni], acc[mi][ni], 0, 0, 0);
        }
    };

    STAGE(0, 0);
    #pragma unroll 1
    for (int t = 0; t < 16; ++t) {
        if (t + 1 < 16) {
            STAGE(t + 1, (t + 1) & 1);
            asm volatile("s_waitcnt vmcnt(8)" : : : "memory");
        } else {
            asm volatile("s_waitcnt vmcnt(0)" : : : "memory");
        }
        __builtin_amdgcn_s_barrier();
        COMPUTE(t & 1);
        __builtin_amdgcn_s_barrier();
    }

    #pragma unroll
    for (int mi = 0; mi < 4; ++mi)
        #pragma unroll
        for (int ni = 0; ni < 4; ++ni) {
            int d = n0 + wc * 64 + ni * 16 + l15;
            #pragma unroll
            for (int r = 0; r < 4; ++r) {
                int row = m0 + wr * 64 + mi * 16 + l4 * 4 + r;
                out[(size_t)row * 1024 + d] = acc[mi][ni][r];
            }
        }
}

// -------------------------------------------------------------------------
extern "C" void kernel_launch(void* const* d_in, const int* in_sizes, int n_in,
                              void* d_out, int out_size, void* d_ws, size_t ws_size,
                              hipStream_t stream)
{
    const float* x    = (const float*)d_in[0];
    const float* h0   = (const float*)d_in[1];
    const float* Win  = (const float*)d_in[2];
    const float* Wx   = (const float*)d_in[3];
    const float* Wh   = (const float*)d_in[4];
    const float* bias = (const float*)d_in[5];
    const float* Wout = (const float*)d_in[6];

    float* out  = (float*)d_out;
    float* hfin = out + (size_t)BT_ * DIM_;

    // ws layout (54 MB total):
    char* ws = (char*)d_ws;
    ushort_t* pxb   = (ushort_t*)(ws);                      // 16 MB bf16 px
    ushort_t* gtb   = (ushort_t*)(ws + 16777216);           // 16 MB bf16 gate
    ushort_t* xw    = (ushort_t*)(ws + 33554432);           // 16 MB bf16 x
    ushort_t* ogb   = xw;                                   // og aliases xw (dead after K1)
    ushort_t* Winb  = (ushort_t*)(ws + 50331648);           //  4 MB
    ushort_t* Woutb = (ushort_t*)(ws + 54525952);           //  2 MB

    cvt3_kernel<<<5632, 256, 0, stream>>>(x, Win, Wout, xw, Winb, Woutb);

    gemm_in_kernel<<<dim3(16, 64), 256, 0, stream>>>(xw, Winb, Wx, pxb, gtb);
    scan_kernel<<<64 * NCHUNK, 64, 0, stream>>>(pxb, gtb, ogb, Wh, bias, h0, hfin);
    gemm_out_kernel<<<dim3(8, 64), 256, 0, stream>>>(ogb, Woutb, out);
}